// Round 16
// baseline (155.013 us; speedup 1.0000x reference)
//
#include <hip/hip_runtime.h>
#include <hip/hip_fp16.h>
#include <math.h>

// Problem dims: B=16, N=64, D=512, H=512, R=8, HK=64, G=2
// Outputs: f_emb [16,64,64,64,2] (8388608 f32) then logits [16,512] (8192 f32)

typedef _Float16 f16x8 __attribute__((ext_vector_type(8)));
typedef float f32x4 __attribute__((ext_vector_type(4)));

__device__ __forceinline__ unsigned short f2h(float x) {
  _Float16 h = (_Float16)x;
  return __builtin_bit_cast(unsigned short, h);
}

// fragment scatter map for 16x16x32 (row16, kr in 0..31):
//   lane = (row&15) + (((kr>>2)&3)<<4) ; j = (kr&3) + (((kr>>4)&1)<<2)
__device__ __forceinline__ int fragoff(int row, int kr) {
  return (((row & 15) + (((kr >> 2) & 3) << 4)) << 3) + (kr & 3) + (((kr >> 4) & 1) << 2);
}

// ---------------- workspace layout ----------------
#define WS_NRM 0
#define WS_VT  32
#define WS_QT  (WS_VT + 524288)
#define WS_AT  (WS_QT + 524288)
#define WS_LP  (WS_AT + 524288)
#define WS_LR  (WS_LP + 524288)
#define WS_PRT (WS_LR + 8192)
#define WS_H   (WS_PRT + 1280)
#define H_VRL 0
#define H_QR2 524288
#define H_AR2 1048576
#define H_T2  1572864
#define H_AT16 5767168
#define H_IN16 6291456
#define H_WB16 7864320
#define H_WN16 8650752
#define H_RP16 9175040

// ---------------- K0a: norm partials ----------------
__global__ __launch_bounds__(256) void k_norms_part(
    const float* __restrict__ Vv, const float* __restrict__ Vq, const float* __restrict__ Va,
    const float* __restrict__ Vnv, const float* __restrict__ Vnqa, float* __restrict__ prt)
{
  const int bx = blockIdx.x;
  int n, j;
  const float* base;
  if (bx < 192) {
    n = bx >> 6; j = bx & 63;
    base = (n == 0 ? Vv : n == 1 ? Vq : Va) + j * 4096;
  } else {
    int t = bx - 192;
    n = 3 + (t >> 3); j = t & 7;
    base = (n < 11 ? Vnv + (n - 3) * 32768 : Vnqa + (n - 11) * 32768) + j * 4096;
  }
  const float4* p4 = (const float4*)base;
  float s = 0.f;
  #pragma unroll
  for (int i = 0; i < 4; ++i) {
    float4 x = p4[threadIdx.x + i * 256];
    s += x.x * x.x + x.y * x.y + x.z * x.z + x.w * x.w;
  }
  __shared__ float red[256];
  red[threadIdx.x] = s; __syncthreads();
  for (int off = 128; off > 0; off >>= 1) {
    if (threadIdx.x < off) red[threadIdx.x] += red[threadIdx.x + off];
    __syncthreads();
  }
  if (threadIdx.x == 0) prt[n * 64 + j] = red[0];
}

// ---------------- K0b: finalize norms ----------------
__global__ __launch_bounds__(64) void k_norms_fin(const float* __restrict__ prt, float* __restrict__ wsn)
{
  const int n = blockIdx.x, t = threadIdx.x;
  const int cnt = (n < 3) ? 64 : 8;
  float s = (t < cnt) ? prt[n * 64 + t] : 0.f;
  #pragma unroll
  for (int off = 32; off > 0; off >>= 1) s += __shfl_down(s, off);
  if (t == 0) wsn[n] = sqrtf(s);
}

// ---------------- KC: merged conversions (inconv | wconv | wnconv) ----------------
__global__ __launch_bounds__(256) void k_conv_all(
    const float* __restrict__ v, const float* __restrict__ q, const float* __restrict__ a,
    const float* __restrict__ Wv, const float* __restrict__ Wq, const float* __restrict__ Wa,
    const float* __restrict__ gv, const float* __restrict__ gq, const float* __restrict__ ga,
    const float* __restrict__ Vnv, const float* __restrict__ Vnqa,
    const float* __restrict__ gnv, const float* __restrict__ gnqa,
    const float* __restrict__ wsn,
    unsigned short* __restrict__ IN16, unsigned short* __restrict__ WB16,
    unsigned short* __restrict__ WN16)
{
  const int bx = blockIdx.x;
  if (bx < 192) {
    const int z = bx >> 6, sub = bx & 63;
    const float4* src = (const float4*)((z == 0) ? v : (z == 1) ? q : a);
    #pragma unroll
    for (int i = 0; i < 8; ++i) {
      int f = sub * 2048 + threadIdx.x + i * 256;
      int row = f >> 7, d0 = (f & 127) * 4;
      float4 x = src[f];
      ushort4 pk;
      pk.x = f2h(x.x); pk.y = f2h(x.y); pk.z = f2h(x.z); pk.w = f2h(x.w);
      int lanep = (row & 15) + (((d0 >> 2) & 3) << 4);
      int jb = ((d0 >> 4) & 1) << 2;
      size_t off = ((size_t)(z * 64 + (row >> 4)) * 16 + (d0 >> 5)) * 512 + lanep * 8 + jb;
      *(ushort4*)&IN16[off] = pk;
    }
  } else if (bx < 288) {
    const int t = bx - 192;
    const int z = t >> 5, sub = t & 31;
    const float4* src = (const float4*)((z == 0) ? Wv : (z == 1) ? Wq : Wa);
    const float scale = ((z == 0) ? gv[0] : (z == 1) ? gq[0] : ga[0]) / wsn[z];
    #pragma unroll
    for (int i = 0; i < 8; ++i) {
      int f = sub * 2048 + threadIdx.x + i * 256;
      int n = f >> 7, d0 = (f & 127) * 4;
      float4 x = src[f];
      ushort4 pk;
      pk.x = f2h(x.x * scale); pk.y = f2h(x.y * scale);
      pk.z = f2h(x.z * scale); pk.w = f2h(x.w * scale);
      int lanep = (n & 15) + (((d0 >> 2) & 3) << 4);
      int jb = ((d0 >> 4) & 1) << 2;
      size_t off = ((size_t)(z * 32 + (n >> 4)) * 16 + (d0 >> 5)) * 512 + lanep * 8 + jb;
      *(ushort4*)&WB16[off] = pk;
    }
  } else {
    const int t = bx - 288;
    const int zr = t >> 2, sub = t & 3;
    const int zq = zr >> 3, r = zr & 7;
    const float4* src = (const float4*)((zq == 0 ? Vnv : Vnqa) + (size_t)r * 32768);
    const float scale = (zq == 0) ? (gnv[r] / wsn[3 + r]) : (gnqa[r] / wsn[11 + r]);
    #pragma unroll
    for (int i = 0; i < 8; ++i) {
      int f = sub * 2048 + threadIdx.x + i * 256;
      int n = f >> 7, d0 = (f & 127) * 4;
      float4 x = src[f];
      ushort4 pk;
      pk.x = f2h(x.x * scale); pk.y = f2h(x.y * scale);
      pk.z = f2h(x.z * scale); pk.w = f2h(x.w * scale);
      int lanep = (n & 15) + (((d0 >> 2) & 3) << 4);
      int jb = ((d0 >> 4) & 1) << 2;
      size_t off = ((size_t)(zr * 4 + (n >> 4)) * 16 + (d0 >> 5)) * 512 + lanep * 8 + jb;
      *(ushort4*)&WN16[off] = pk;
    }
  }
}

// ---------------- KT: repack T via LDS bounce ----------------
__global__ __launch_bounds__(256) void k_repack2b(const float* __restrict__ Tg, unsigned short* __restrict__ T2)
{
  const int r = blockIdx.x >> 4, lB = blockIdx.x & 15;
  __shared__ unsigned short lds[32768];
  const int tid = threadIdx.x;

  #pragma unroll
  for (int i = 0; i < 32; ++i) {
    int f = tid + i * 256;
    int lpair = f & 1, k = (f >> 1) & 63, h = f >> 7;
    int l0 = lB * 4 + lpair * 2;
    const float4 x = *(const float4*)(Tg + ((size_t)((r * 64 + h) * 64 + k) * 64 + l0) * 2);
    const int el = fragoff(k & 15, h & 31);
    const int ks = h >> 5;
    const int ntr0 = (l0 & 3) * 4 + (k >> 4);
    const int ntr1 = ((l0 + 1) & 3) * 4 + (k >> 4);
    lds[((0 * 16 + ntr0) * 2 + ks) * 512 + el] = f2h(x.x);
    lds[((1 * 16 + ntr0) * 2 + ks) * 512 + el] = f2h(x.y);
    lds[((0 * 16 + ntr1) * 2 + ks) * 512 + el] = f2h(x.z);
    lds[((1 * 16 + ntr1) * 2 + ks) * 512 + el] = f2h(x.w);
  }
  __syncthreads();

  #pragma unroll
  for (int g = 0; g < 2; ++g) {
    unsigned short* dst = T2 + ((size_t)(g * 8 + r) * 256 + lB * 16) * 1024;
    const float4* s = (const float4*)&lds[g * 16384];
    float4* d = (float4*)dst;
    #pragma unroll
    for (int i = 0; i < 8; ++i) d[tid + i * 256] = s[tid + i * 256];
  }
}

// ---------------- K1: proj via fp16 MFMA (also emits AT16 when z==2) ----------------
__global__ __launch_bounds__(256) void k_proj16(
    const unsigned short* __restrict__ IN16, const unsigned short* __restrict__ WB16,
    const float* __restrict__ bv, const float* __restrict__ bq, const float* __restrict__ ba,
    float* __restrict__ ov, float* __restrict__ oq, float* __restrict__ oa,
    unsigned short* __restrict__ RP16, unsigned short* __restrict__ AT16)
{
  const int nB = blockIdx.x, mB = blockIdx.y, z = blockIdx.z;
  const float* bias = (z == 0) ? bv : (z == 1) ? bq : ba;
  float* out = (z == 0) ? ov : (z == 1) ? oq : oa;
  const int tid = threadIdx.x, lane = tid & 63;
  const int w = __builtin_amdgcn_readfirstlane(tid >> 6);

  f32x4 c[4];
  #pragma unroll
  for (int mt = 0; mt < 4; ++mt) c[mt] = (f32x4){0.f, 0.f, 0.f, 0.f};

  #pragma unroll 4
  for (int ks = 0; ks < 16; ++ks) {
    f16x8 af[4], bfr;
    #pragma unroll
    for (int mt = 0; mt < 4; ++mt)
      af[mt] = *(const f16x8*)&IN16[((size_t)(z * 64 + mB * 4 + mt) * 16 + ks) * 512 + lane * 8];
    bfr = *(const f16x8*)&WB16[((size_t)(z * 32 + nB * 4 + w) * 16 + ks) * 512 + lane * 8];
    #pragma unroll
    for (int mt = 0; mt < 4; ++mt)
      c[mt] = __builtin_amdgcn_mfma_f32_16x16x32_f16(af[mt], bfr, c[mt], 0, 0, 0);
  }

  const int col = nB * 64 + w * 16 + (lane & 15);
  const float bb = bias[col];
  #pragma unroll
  for (int mt = 0; mt < 4; ++mt)
    #pragma unroll
    for (int i = 0; i < 4; ++i) {
      const int row = mB * 64 + mt * 16 + 4 * (lane >> 4) + i;
      float val = fmaxf(c[mt][i] + bb, 0.f);
      unsigned short hv = f2h(val);
      out[(size_t)row * 512 + col] = val;
      RP16[((size_t)(z * 64 + (row >> 4)) * 16 + (col >> 5)) * 512 + fragoff(row, col & 31)] = hv;
      if (z == 2) {
        const int m = row & 63;
        AT16[(size_t)(row >> 6) * 32768 + ((col >> 4) * 2 + (m >> 5)) * 512 + fragoff(col & 15, m & 31)] = hv;
      }
    }
}

// ---------------- K2: per-rank proj via fp16 MFMA ----------------
__global__ __launch_bounds__(256) void k_rproj16(
    const unsigned short* __restrict__ RP16, const unsigned short* __restrict__ WN16,
    const float* __restrict__ bnv, const float* __restrict__ bnqa,
    unsigned short* __restrict__ vrLin, unsigned short* __restrict__ qrT2,
    unsigned short* __restrict__ arT2)
{
  const int r = blockIdx.x, mB = blockIdx.y, z = blockIdx.z;
  const int zq = (z == 0) ? 0 : 1;
  const float* bias = ((z == 0) ? bnv : bnqa) + r * 64;
  const int tid = threadIdx.x, lane = tid & 63;
  const int w = __builtin_amdgcn_readfirstlane(tid >> 6);
  const int wm = w >> 1, wn = w & 1;

  f32x4 c[2][2];
  #pragma unroll
  for (int mi = 0; mi < 2; ++mi)
    #pragma unroll
    for (int ni = 0; ni < 2; ++ni) c[mi][ni] = (f32x4){0.f, 0.f, 0.f, 0.f};

  #pragma unroll 4
  for (int ks = 0; ks < 16; ++ks) {
    f16x8 af[2], bf[2];
    #pragma unroll
    for (int mi = 0; mi < 2; ++mi)
      af[mi] = *(const f16x8*)&RP16[((size_t)(z * 64 + mB * 4 + wm * 2 + mi) * 16 + ks) * 512 + lane * 8];
    #pragma unroll
    for (int ni = 0; ni < 2; ++ni)
      bf[ni] = *(const f16x8*)&WN16[((size_t)((zq * 8 + r) * 4 + wn * 2 + ni) * 16 + ks) * 512 + lane * 8];
    #pragma unroll
    for (int mi = 0; mi < 2; ++mi)
      #pragma unroll
      for (int ni = 0; ni < 2; ++ni)
        c[mi][ni] = __builtin_amdgcn_mfma_f32_16x16x32_f16(af[mi], bf[ni], c[mi][ni], 0, 0, 0);
  }

  #pragma unroll
  for (int mi = 0; mi < 2; ++mi)
    #pragma unroll
    for (int ni = 0; ni < 2; ++ni) {
      const int n = (wn * 2 + ni) * 16 + (lane & 15);
      const float bb2 = bias[n];
      #pragma unroll
      for (int i = 0; i < 4; ++i) {
        const int mm = mB * 64 + (wm * 2 + mi) * 16 + 4 * (lane >> 4) + i;
        const int bb = mm >> 6, nr = mm & 63;
        float val = fmaxf(c[mi][ni][i] + bb2, 0.f);
        unsigned short hv = f2h(val);
        if (z == 0)
          vrLin[((size_t)(bb * 8 + r) * 64 + nr) * 64 + n] = hv;
        else if (z == 1)
          qrT2[(size_t)(bb * 8 + r) * 4096 + ((nr >> 4) * 2 + (n >> 5)) * 512 + fragoff(nr, n & 31)] = hv;
        else
          arT2[(size_t)(((bb * 8 + r) * 2 + (n >> 5)) * 4 + (nr >> 4)) * 512 + fragoff(nr, n & 31)] = hv;
      }
    }
}

// ---------------- K3: FUSED Tucker (r15 base + 2-deep T2 register prefetch pipeline) ----------------
__global__ __launch_bounds__(512) void k_tucker16(
    const unsigned short* __restrict__ vrLin, const unsigned short* __restrict__ qrT2,
    const unsigned short* __restrict__ arT2, const unsigned short* __restrict__ T2,
    float* __restrict__ fout)
{
  const int b = blockIdx.x, vt = blockIdx.y, g = blockIdx.z;
  const int tid = threadIdx.x, lane = tid & 63;
  const int w = __builtin_amdgcn_readfirstlane(tid >> 6);

  __shared__ __align__(16) unsigned short UA[16384];
  __shared__ __align__(16) unsigned short QB[4096];
  __shared__ __align__(16) unsigned short AB[2048];
  __shared__ __align__(16) unsigned short CC[16640];  // [qh][8320]
  __shared__ __align__(16) unsigned short VRL[512];

  f32x4 f[2][2][4];
  #pragma unroll
  for (int qh = 0; qh < 2; ++qh)
    #pragma unroll
    for (int qt = 0; qt < 2; ++qt)
      #pragma unroll
      for (int nt = 0; nt < 4; ++nt)
        f[qh][qt][nt] = (f32x4){0.f, 0.f, 0.f, 0.f};

  for (int r = 0; r < 8; ++r) {
    if (tid < 64)
      *(float4*)&VRL[tid * 8] =
          ((const float4*)(vrLin + (size_t)(b * 8 + r) * 4096 + vt * 512))[tid];
    *(float4*)&QB[tid * 8] = ((const float4*)(qrT2 + (size_t)(b * 8 + r) * 4096))[tid];
    __syncthreads();  // B1

    f16x8 af1[2];
    #pragma unroll
    for (int ks = 0; ks < 2; ++ks)
      #pragma unroll
      for (int j = 0; j < 8; ++j) {
        const int kr = (j & 3) + ((lane >> 4) & 3) * 4 + (j >> 2) * 16;
        af1[ks][j] = __builtin_bit_cast(_Float16, VRL[(lane & 7) * 64 + ks * 32 + kr]);
      }

    for (int lc = 0; lc < 2; ++lc) {
      if (tid < 256)
        ((float4*)AB)[tid] = ((const float4*)(arT2 + ((size_t)((b * 8 + r) * 2 + lc)) * 2048))[tid];

      const unsigned short* tb = T2 + ((size_t)((g * 8 + r) * 256 + lc * 128 + w * 16)) * 1024;

      // ---- stage1 with 2-deep register prefetch (bufA/bufB alternate per tg) ----
      f16x8 bufA[4][2], bufB[4][2];
      #pragma unroll
      for (int tt = 0; tt < 4; ++tt)
        #pragma unroll
        for (int ks = 0; ks < 2; ++ks)
          bufA[tt][ks] = *(const f16x8*)&tb[(size_t)tt * 1024 + ks * 512 + lane * 8];

      #pragma unroll
      for (int tg = 0; tg < 4; ++tg) {
        // issue next tg's loads into the other buffer BEFORE consuming current
        if (tg < 3) {
          #pragma unroll
          for (int tt = 0; tt < 4; ++tt)
            #pragma unroll
            for (int ks = 0; ks < 2; ++ks) {
              f16x8 ld = *(const f16x8*)&tb[(size_t)((tg + 1) * 4 + tt) * 1024 + ks * 512 + lane * 8];
              if (tg & 1) bufA[tt][ks] = ld; else bufB[tt][ks] = ld;
            }
        }
        f32x4 d[4];
        #pragma unroll
        for (int tt = 0; tt < 4; ++tt) d[tt] = (f32x4){0.f, 0.f, 0.f, 0.f};
        #pragma unroll
        for (int tt = 0; tt < 4; ++tt)
          #pragma unroll
          for (int ks = 0; ks < 2; ++ks) {
            const f16x8 cur = (tg & 1) ? bufB[tt][ks] : bufA[tt][ks];
            d[tt] = __builtin_amdgcn_mfma_f32_16x16x32_f16(af1[ks], cur, d[tt], 0, 0, 0);
          }
        if (lane < 32) {
          #pragma unroll
          for (int tt = 0; tt < 4; ++tt) {
            const int t = w * 16 + tg * 4 + tt;
            const int lrel = t >> 2;
            const int k0 = (t & 3) * 16 + (lane & 15);
            #pragma unroll
            for (int i = 0; i < 4; ++i) {
              const int v = 4 * (lane >> 4) + i;
              const int row = lrel * 8 + v;
              int off = fragoff(row & 15, k0 & 31);
              int blk = off >> 3;
              blk ^= (blk >> 4) & 3;
              UA[(row >> 4) * 1024 + (k0 >> 5) * 512 + blk * 8 + (off & 7)] = f2h(d[tt][i]);
            }
          }
        }
      }
      __syncthreads();  // B2: UA + AB ready

      f16x8 b3[4], a2[2][2];
      #pragma unroll
      for (int nt = 0; nt < 4; ++nt)
        b3[nt] = *(const f16x8*)&AB[nt * 512 + lane * 8];
      const int lswz = (lane ^ ((lane >> 4) & 3)) * 8;
      #pragma unroll
      for (int mi = 0; mi < 2; ++mi)
        #pragma unroll
        for (int ks = 0; ks < 2; ++ks)
          a2[mi][ks] = *(const f16x8*)&UA[(w * 2 + mi) * 1024 + ks * 512 + lswz];

      // ---- stage2 for BOTH qh ----
      #pragma unroll
      for (int qh = 0; qh < 2; ++qh) {
        f32x4 c2[2][2];
        #pragma unroll
        for (int mi = 0; mi < 2; ++mi)
          #pragma unroll
          for (int nt = 0; nt < 2; ++nt)
            c2[mi][nt] = (f32x4){0.f, 0.f, 0.f, 0.f};

        f16x8 b2[2][2];
        #pragma unroll
        for (int nt = 0; nt < 2; ++nt)
          #pragma unroll
          for (int ks = 0; ks < 2; ++ks)
            b2[nt][ks] = *(const f16x8*)&QB[(qh * 2 + nt) * 1024 + ks * 512 + lane * 8];

        #pragma unroll
        for (int mi = 0; mi < 2; ++mi)
          #pragma unroll
          for (int nt = 0; nt < 2; ++nt)
            #pragma unroll
            for (int ks = 0; ks < 2; ++ks)
              c2[mi][nt] = __builtin_amdgcn_mfma_f32_16x16x32_f16(a2[mi][ks], b2[nt][ks], c2[mi][nt], 0, 0, 0);

        #pragma unroll
        for (int mi = 0; mi < 2; ++mi)
          #pragma unroll
          for (int nt = 0; nt < 2; ++nt)
            #pragma unroll
            for (int i = 0; i < 4; ++i) {
              const int row = (w * 2 + mi) * 16 + 4 * (lane >> 4) + i;
              const int l = row >> 3, v = row & 7;
              CC[qh * 8320 + (nt * 8 + v) * 520 + fragoff(lane & 15, l)] = f2h(c2[mi][nt][i]);
            }
      }
      __syncthreads();  // B3

      // ---- stage3 for BOTH qh ----
      #pragma unroll
      for (int qh = 0; qh < 2; ++qh) {
        f16x8 a3[2];
        #pragma unroll
        for (int qt = 0; qt < 2; ++qt)
          a3[qt] = *(const f16x8*)&CC[qh * 8320 + (qt * 8 + w) * 520 + lane * 8];

        #pragma unroll
        for (int qt = 0; qt < 2; ++qt)
          #pragma unroll
          for (int nt = 0; nt < 4; ++nt)
            f[qh][qt][nt] = __builtin_amdgcn_mfma_f32_16x16x32_f16(a3[qt], b3[nt], f[qh][qt][nt], 0, 0, 0);
      }
      __syncthreads();  // B4
    }
  }

  #pragma unroll
  for (int qh = 0; qh < 2; ++qh)
    #pragma unroll
    for (int qt = 0; qt < 2; ++qt)
      #pragma unroll
      for (int nt = 0; nt < 4; ++nt)
        #pragma unroll
        for (int i = 0; i < 4; ++i) {
          const int q = qh * 32 + qt * 16 + 4 * (lane >> 4) + i;
          const int m = nt * 16 + (lane & 15);
          size_t addr = ((((size_t)b * 64 + vt * 8 + w) * 64 + q) * 64 + m) * 2 + g;
          fout[addr] = f[qh][qt][nt][i];
        }
}

// ---------------- K4: logits via MFMA per (b,v) ----------------
__global__ __launch_bounds__(512) void k_logits2(
    const float* __restrict__ vt, const float* __restrict__ qt,
    const unsigned short* __restrict__ AT16, const float* __restrict__ fout,
    float* __restrict__ Lp)
{
  const int v = blockIdx.x, b = blockIdx.y;
  const int tid = threadIdx.x, lane = tid & 63;
  const int w = __builtin_amdgcn_readfirstlane(tid >> 6);

  __shared__ __align__(16) unsigned int FAu[2048];

  {
    const float4* fo4 = (const float4*)(fout + ((size_t)(b * 64 + v)) * 8192);
    #pragma unroll
    for (int i = 0; i < 4; ++i) {
      int fi = tid + i * 512;
      int q = fi >> 5, mpair = fi & 31;
      float4 x = fo4[fi];
      float s0 = x.x + x.y, s1 = x.z + x.w;
      int m0 = mpair * 2;
      int off = fragoff(q & 15, m0 & 31);
      int idx2 = (((q >> 4) * 2 + (m0 >> 5)) * 512 + off) >> 1;
      unsigned int pk = (unsigned int)f2h(s0) | ((unsigned int)f2h(s1) << 16);
      FAu[idx2] = pk;
    }
  }
  __syncthreads();

  const unsigned short* FAh = (const unsigned short*)FAu;

  f16x8 af[4][2], bf[4][2];
  #pragma unroll
  for (int mt = 0; mt < 4; ++mt)
    #pragma unroll
    for (int ks = 0; ks < 2; ++ks)
      af[mt][ks] = *(const f16x8*)&FAh[(mt * 2 + ks) * 512 + lane * 8];
  #pragma unroll
  for (int nt = 0; nt < 4; ++nt)
    #pragma unroll
    for (int ks = 0; ks < 2; ++ks)
      bf[nt][ks] = *(const f16x8*)&AT16[(size_t)((b * 32 + w * 4 + nt) * 2 + ks) * 512 + lane * 8];

  f32x4 c[4][4];
  #pragma unroll
  for (int mt = 0; mt < 4; ++mt)
    #pragma unroll
    for (int nt = 0; nt < 4; ++nt)
      c[mt][nt] = (f32x4){0.f, 0.f, 0.f, 0.f};

  #pragma unroll
  for (int mt = 0; mt < 4; ++mt)
    #pragma unroll
    for (int nt = 0; nt < 4; ++nt)
      #pragma unroll
      for (int ks = 0; ks < 2; ++ks)
        c[mt][nt] = __builtin_amdgcn_mfma_f32_16x16x32_f16(af[mt][ks], bf[nt][ks], c[mt][nt], 0, 0, 0);

  const int gr = lane >> 4, dl = lane & 15;
  #pragma unroll
  for (int nt = 0; nt < 4; ++nt) {
    const int d = w * 64 + nt * 16 + dl;
    float partial = 0.f;
    #pragma unroll
    for (int mt = 0; mt < 4; ++mt) {
      #pragma unroll
      for (int i = 0; i < 4; ++i) {
        const int q = mt * 16 + gr * 4 + i;
        partial += qt[(b * 64 + q) * 512 + d] * c[mt][nt][i];
      }
    }
    partial += __shfl_xor(partial, 16);
    partial += __shfl_xor(partial, 32);
    const float val = vt[(b * 64 + v) * 512 + d] * partial;
    if (lane < 16) Lp[((size_t)(b * 64 + v)) * 512 + d] = val;
  }
}

// ---------------- K5: reduce logits over v ----------------
__global__ __launch_bounds__(512) void k_lred(const float* __restrict__ Lp, float* __restrict__ Lraw)
{
  const int b = blockIdx.x, d = threadIdx.x;
  float s = 0.f;
  for (int v = 0; v < 64; ++v) s += Lp[(size_t)(b * 64 + v) * 512 + d];
  Lraw[b * 512 + d] = s;
}

// ---------------- K6: batchnorm over batch dim ----------------
__global__ __launch_bounds__(512) void k_bn(
    const float* __restrict__ Lraw, const float* __restrict__ gamma,
    const float* __restrict__ beta, float* __restrict__ lout)
{
  const int d = threadIdx.x;
  float x[16]; float mu = 0.f;
  #pragma unroll
  for (int b = 0; b < 16; ++b) { x[b] = Lraw[b * 512 + d]; mu += x[b]; }
  mu *= (1.f / 16.f);
  float var = 0.f;
  #pragma unroll
  for (int b = 0; b < 16; ++b) { float t = x[b] - mu; var += t * t; }
  var *= (1.f / 16.f);
  const float sc = gamma[d] / sqrtf(var + 1e-5f);
  const float bt = beta[d];
  #pragma unroll
  for (int b = 0; b < 16; ++b) lout[b * 512 + d] = (x[b] - mu) * sc + bt;
}

extern "C" void kernel_launch(void* const* d_in, const int* in_sizes, int n_in,
                              void* d_out, int out_size, void* d_ws, size_t ws_size,
                              hipStream_t stream)
{
  const float* v    = (const float*)d_in[0];
  const float* q    = (const float*)d_in[1];
  const float* a    = (const float*)d_in[2];
  const float* Vv   = (const float*)d_in[3];
  const float* gv   = (const float*)d_in[4];
  const float* bv   = (const float*)d_in[5];
  const float* Vq   = (const float*)d_in[6];
  const float* gq   = (const float*)d_in[7];
  const float* bq   = (const float*)d_in[8];
  const float* Va   = (const float*)d_in[9];
  const float* ga   = (const float*)d_in[10];
  const float* ba   = (const float*)d_in[11];
  const float* Vnv  = (const float*)d_in[12];
  const float* gnv  = (const float*)d_in[13];
  const float* bnv  = (const float*)d_in[14];
  const float* Vnqa = (const float*)d_in[15];
  const float* gnqa = (const float*)d_in[16];
  const float* bnqa = (const float*)d_in[17];
  const float* Tg   = (const float*)d_in[18];
  const float* gamma= (const float*)d_in[19];
  const float* beta = (const float*)d_in[20];

  float* ws   = (float*)d_ws;
  unsigned short* hb = (unsigned short*)(ws + WS_H);
  float* fout = (float*)d_out;
  float* lout = fout + (size_t)16 * 64 * 64 * 64 * 2;

  k_norms_part<<<320, 256, 0, stream>>>(Vv, Vq, Va, Vnv, Vnqa, ws + WS_PRT);
  k_norms_fin<<<19, 64, 0, stream>>>(ws + WS_PRT, ws + WS_NRM);
  k_conv_all<<<352, 256, 0, stream>>>(v, q, a, Vv, Vq, Va, gv, gq, ga,
                                      Vnv, Vnqa, gnv, gnqa, ws + WS_NRM,
                                      hb + H_IN16, hb + H_WB16, hb + H_WN16);
  k_repack2b<<<128, 256, 0, stream>>>(Tg, hb + H_T2);
  k_proj16<<<dim3(8, 16, 3), 256, 0, stream>>>(hb + H_IN16, hb + H_WB16, bv, bq, ba,
                                               ws + WS_VT, ws + WS_QT, ws + WS_AT,
                                               hb + H_RP16, hb + H_AT16);
  k_rproj16<<<dim3(8, 16, 3), 256, 0, stream>>>(hb + H_RP16, hb + H_WN16, bnv, bnqa,
                                                hb + H_VRL, hb + H_QR2, hb + H_AR2);
  k_tucker16<<<dim3(16, 8, 2), 512, 0, stream>>>(hb + H_VRL, hb + H_QR2, hb + H_AR2,
                                                 hb + H_T2, fout);
  k_logits2<<<dim3(64, 16), 512, 0, stream>>>(ws + WS_VT, ws + WS_QT,
                                              hb + H_AT16, fout, ws + WS_LP);
  k_lred<<<16, 512, 0, stream>>>(ws + WS_LP, ws + WS_LR);
  k_bn<<<1, 512, 0, stream>>>(ws + WS_LR, gamma, beta, lout);
}

// Round 17
// 151.656 us; speedup vs baseline: 1.0221x; 1.0221x over previous
//
#include <hip/hip_runtime.h>
#include <hip/hip_fp16.h>
#include <math.h>

// Problem dims: B=16, N=64, D=512, H=512, R=8, HK=64, G=2
// Outputs: f_emb [16,64,64,64,2] (8388608 f32) then logits [16,512] (8192 f32)

typedef _Float16 f16x8 __attribute__((ext_vector_type(8)));
typedef float f32x4 __attribute__((ext_vector_type(4)));

__device__ __forceinline__ unsigned short f2h(float x) {
  _Float16 h = (_Float16)x;
  return __builtin_bit_cast(unsigned short, h);
}

// fragment scatter map for 16x16x32 (row16, kr in 0..31):
//   lane = (row&15) + (((kr>>2)&3)<<4) ; j = (kr&3) + (((kr>>4)&1)<<2)
__device__ __forceinline__ int fragoff(int row, int kr) {
  return (((row & 15) + (((kr >> 2) & 3) << 4)) << 3) + (kr & 3) + (((kr >> 4) & 1) << 2);
}

// ---------------- workspace layout ----------------
#define WS_NRM 0
#define WS_VT  32
#define WS_QT  (WS_VT + 524288)
#define WS_AT  (WS_QT + 524288)
#define WS_LP  (WS_AT + 524288)
#define WS_LR  (WS_LP + 524288)
#define WS_PRT (WS_LR + 8192)
#define WS_H   (WS_PRT + 1280)
#define H_VRL 0
#define H_QR2 524288
#define H_AR2 1048576
#define H_T2  1572864
#define H_AT16 5767168
#define H_IN16 6291456
#define H_WB16 7864320
#define H_WN16 8650752
#define H_RP16 9175040

// ---------------- K0a: norm partials ----------------
__global__ __launch_bounds__(256) void k_norms_part(
    const float* __restrict__ Vv, const float* __restrict__ Vq, const float* __restrict__ Va,
    const float* __restrict__ Vnv, const float* __restrict__ Vnqa, float* __restrict__ prt)
{
  const int bx = blockIdx.x;
  int n, j;
  const float* base;
  if (bx < 192) {
    n = bx >> 6; j = bx & 63;
    base = (n == 0 ? Vv : n == 1 ? Vq : Va) + j * 4096;
  } else {
    int t = bx - 192;
    n = 3 + (t >> 3); j = t & 7;
    base = (n < 11 ? Vnv + (n - 3) * 32768 : Vnqa + (n - 11) * 32768) + j * 4096;
  }
  const float4* p4 = (const float4*)base;
  float s = 0.f;
  #pragma unroll
  for (int i = 0; i < 4; ++i) {
    float4 x = p4[threadIdx.x + i * 256];
    s += x.x * x.x + x.y * x.y + x.z * x.z + x.w * x.w;
  }
  __shared__ float red[256];
  red[threadIdx.x] = s; __syncthreads();
  for (int off = 128; off > 0; off >>= 1) {
    if (threadIdx.x < off) red[threadIdx.x] += red[threadIdx.x + off];
    __syncthreads();
  }
  if (threadIdx.x == 0) prt[n * 64 + j] = red[0];
}

// ---------------- K0b: finalize norms ----------------
__global__ __launch_bounds__(64) void k_norms_fin(const float* __restrict__ prt, float* __restrict__ wsn)
{
  const int n = blockIdx.x, t = threadIdx.x;
  const int cnt = (n < 3) ? 64 : 8;
  float s = (t < cnt) ? prt[n * 64 + t] : 0.f;
  #pragma unroll
  for (int off = 32; off > 0; off >>= 1) s += __shfl_down(s, off);
  if (t == 0) wsn[n] = sqrtf(s);
}

// ---------------- KC: merged conversions (inconv | wconv | wnconv) ----------------
__global__ __launch_bounds__(256) void k_conv_all(
    const float* __restrict__ v, const float* __restrict__ q, const float* __restrict__ a,
    const float* __restrict__ Wv, const float* __restrict__ Wq, const float* __restrict__ Wa,
    const float* __restrict__ gv, const float* __restrict__ gq, const float* __restrict__ ga,
    const float* __restrict__ Vnv, const float* __restrict__ Vnqa,
    const float* __restrict__ gnv, const float* __restrict__ gnqa,
    const float* __restrict__ wsn,
    unsigned short* __restrict__ IN16, unsigned short* __restrict__ WB16,
    unsigned short* __restrict__ WN16)
{
  const int bx = blockIdx.x;
  if (bx < 192) {
    const int z = bx >> 6, sub = bx & 63;
    const float4* src = (const float4*)((z == 0) ? v : (z == 1) ? q : a);
    #pragma unroll
    for (int i = 0; i < 8; ++i) {
      int f = sub * 2048 + threadIdx.x + i * 256;
      int row = f >> 7, d0 = (f & 127) * 4;
      float4 x = src[f];
      ushort4 pk;
      pk.x = f2h(x.x); pk.y = f2h(x.y); pk.z = f2h(x.z); pk.w = f2h(x.w);
      int lanep = (row & 15) + (((d0 >> 2) & 3) << 4);
      int jb = ((d0 >> 4) & 1) << 2;
      size_t off = ((size_t)(z * 64 + (row >> 4)) * 16 + (d0 >> 5)) * 512 + lanep * 8 + jb;
      *(ushort4*)&IN16[off] = pk;
    }
  } else if (bx < 288) {
    const int t = bx - 192;
    const int z = t >> 5, sub = t & 31;
    const float4* src = (const float4*)((z == 0) ? Wv : (z == 1) ? Wq : Wa);
    const float scale = ((z == 0) ? gv[0] : (z == 1) ? gq[0] : ga[0]) / wsn[z];
    #pragma unroll
    for (int i = 0; i < 8; ++i) {
      int f = sub * 2048 + threadIdx.x + i * 256;
      int n = f >> 7, d0 = (f & 127) * 4;
      float4 x = src[f];
      ushort4 pk;
      pk.x = f2h(x.x * scale); pk.y = f2h(x.y * scale);
      pk.z = f2h(x.z * scale); pk.w = f2h(x.w * scale);
      int lanep = (n & 15) + (((d0 >> 2) & 3) << 4);
      int jb = ((d0 >> 4) & 1) << 2;
      size_t off = ((size_t)(z * 32 + (n >> 4)) * 16 + (d0 >> 5)) * 512 + lanep * 8 + jb;
      *(ushort4*)&WB16[off] = pk;
    }
  } else {
    const int t = bx - 288;
    const int zr = t >> 2, sub = t & 3;
    const int zq = zr >> 3, r = zr & 7;
    const float4* src = (const float4*)((zq == 0 ? Vnv : Vnqa) + (size_t)r * 32768);
    const float scale = (zq == 0) ? (gnv[r] / wsn[3 + r]) : (gnqa[r] / wsn[11 + r]);
    #pragma unroll
    for (int i = 0; i < 8; ++i) {
      int f = sub * 2048 + threadIdx.x + i * 256;
      int n = f >> 7, d0 = (f & 127) * 4;
      float4 x = src[f];
      ushort4 pk;
      pk.x = f2h(x.x * scale); pk.y = f2h(x.y * scale);
      pk.z = f2h(x.z * scale); pk.w = f2h(x.w * scale);
      int lanep = (n & 15) + (((d0 >> 2) & 3) << 4);
      int jb = ((d0 >> 4) & 1) << 2;
      size_t off = ((size_t)(zr * 4 + (n >> 4)) * 16 + (d0 >> 5)) * 512 + lanep * 8 + jb;
      *(ushort4*)&WN16[off] = pk;
    }
  }
}

// ---------------- KT: repack T via LDS bounce ----------------
__global__ __launch_bounds__(256) void k_repack2b(const float* __restrict__ Tg, unsigned short* __restrict__ T2)
{
  const int r = blockIdx.x >> 4, lB = blockIdx.x & 15;
  __shared__ unsigned short lds[32768];
  const int tid = threadIdx.x;

  #pragma unroll
  for (int i = 0; i < 32; ++i) {
    int f = tid + i * 256;
    int lpair = f & 1, k = (f >> 1) & 63, h = f >> 7;
    int l0 = lB * 4 + lpair * 2;
    const float4 x = *(const float4*)(Tg + ((size_t)((r * 64 + h) * 64 + k) * 64 + l0) * 2);
    const int el = fragoff(k & 15, h & 31);
    const int ks = h >> 5;
    const int ntr0 = (l0 & 3) * 4 + (k >> 4);
    const int ntr1 = ((l0 + 1) & 3) * 4 + (k >> 4);
    lds[((0 * 16 + ntr0) * 2 + ks) * 512 + el] = f2h(x.x);
    lds[((1 * 16 + ntr0) * 2 + ks) * 512 + el] = f2h(x.y);
    lds[((0 * 16 + ntr1) * 2 + ks) * 512 + el] = f2h(x.z);
    lds[((1 * 16 + ntr1) * 2 + ks) * 512 + el] = f2h(x.w);
  }
  __syncthreads();

  #pragma unroll
  for (int g = 0; g < 2; ++g) {
    unsigned short* dst = T2 + ((size_t)(g * 8 + r) * 256 + lB * 16) * 1024;
    const float4* s = (const float4*)&lds[g * 16384];
    float4* d = (float4*)dst;
    #pragma unroll
    for (int i = 0; i < 8; ++i) d[tid + i * 256] = s[tid + i * 256];
  }
}

// ---------------- K1: proj via fp16 MFMA (also emits AT16 when z==2) ----------------
__global__ __launch_bounds__(256) void k_proj16(
    const unsigned short* __restrict__ IN16, const unsigned short* __restrict__ WB16,
    const float* __restrict__ bv, const float* __restrict__ bq, const float* __restrict__ ba,
    float* __restrict__ ov, float* __restrict__ oq, float* __restrict__ oa,
    unsigned short* __restrict__ RP16, unsigned short* __restrict__ AT16)
{
  const int nB = blockIdx.x, mB = blockIdx.y, z = blockIdx.z;
  const float* bias = (z == 0) ? bv : (z == 1) ? bq : ba;
  float* out = (z == 0) ? ov : (z == 1) ? oq : oa;
  const int tid = threadIdx.x, lane = tid & 63;
  const int w = __builtin_amdgcn_readfirstlane(tid >> 6);

  f32x4 c[4];
  #pragma unroll
  for (int mt = 0; mt < 4; ++mt) c[mt] = (f32x4){0.f, 0.f, 0.f, 0.f};

  #pragma unroll 4
  for (int ks = 0; ks < 16; ++ks) {
    f16x8 af[4], bfr;
    #pragma unroll
    for (int mt = 0; mt < 4; ++mt)
      af[mt] = *(const f16x8*)&IN16[((size_t)(z * 64 + mB * 4 + mt) * 16 + ks) * 512 + lane * 8];
    bfr = *(const f16x8*)&WB16[((size_t)(z * 32 + nB * 4 + w) * 16 + ks) * 512 + lane * 8];
    #pragma unroll
    for (int mt = 0; mt < 4; ++mt)
      c[mt] = __builtin_amdgcn_mfma_f32_16x16x32_f16(af[mt], bfr, c[mt], 0, 0, 0);
  }

  const int col = nB * 64 + w * 16 + (lane & 15);
  const float bb = bias[col];
  #pragma unroll
  for (int mt = 0; mt < 4; ++mt)
    #pragma unroll
    for (int i = 0; i < 4; ++i) {
      const int row = mB * 64 + mt * 16 + 4 * (lane >> 4) + i;
      float val = fmaxf(c[mt][i] + bb, 0.f);
      unsigned short hv = f2h(val);
      out[(size_t)row * 512 + col] = val;
      RP16[((size_t)(z * 64 + (row >> 4)) * 16 + (col >> 5)) * 512 + fragoff(row, col & 31)] = hv;
      if (z == 2) {
        const int m = row & 63;
        AT16[(size_t)(row >> 6) * 32768 + ((col >> 4) * 2 + (m >> 5)) * 512 + fragoff(col & 15, m & 31)] = hv;
      }
    }
}

// ---------------- K2: per-rank proj via fp16 MFMA ----------------
__global__ __launch_bounds__(256) void k_rproj16(
    const unsigned short* __restrict__ RP16, const unsigned short* __restrict__ WN16,
    const float* __restrict__ bnv, const float* __restrict__ bnqa,
    unsigned short* __restrict__ vrLin, unsigned short* __restrict__ qrT2,
    unsigned short* __restrict__ arT2)
{
  const int r = blockIdx.x, mB = blockIdx.y, z = blockIdx.z;
  const int zq = (z == 0) ? 0 : 1;
  const float* bias = ((z == 0) ? bnv : bnqa) + r * 64;
  const int tid = threadIdx.x, lane = tid & 63;
  const int w = __builtin_amdgcn_readfirstlane(tid >> 6);
  const int wm = w >> 1, wn = w & 1;

  f32x4 c[2][2];
  #pragma unroll
  for (int mi = 0; mi < 2; ++mi)
    #pragma unroll
    for (int ni = 0; ni < 2; ++ni) c[mi][ni] = (f32x4){0.f, 0.f, 0.f, 0.f};

  #pragma unroll 4
  for (int ks = 0; ks < 16; ++ks) {
    f16x8 af[2], bf[2];
    #pragma unroll
    for (int mi = 0; mi < 2; ++mi)
      af[mi] = *(const f16x8*)&RP16[((size_t)(z * 64 + mB * 4 + wm * 2 + mi) * 16 + ks) * 512 + lane * 8];
    #pragma unroll
    for (int ni = 0; ni < 2; ++ni)
      bf[ni] = *(const f16x8*)&WN16[((size_t)((zq * 8 + r) * 4 + wn * 2 + ni) * 16 + ks) * 512 + lane * 8];
    #pragma unroll
    for (int mi = 0; mi < 2; ++mi)
      #pragma unroll
      for (int ni = 0; ni < 2; ++ni)
        c[mi][ni] = __builtin_amdgcn_mfma_f32_16x16x32_f16(af[mi], bf[ni], c[mi][ni], 0, 0, 0);
  }

  #pragma unroll
  for (int mi = 0; mi < 2; ++mi)
    #pragma unroll
    for (int ni = 0; ni < 2; ++ni) {
      const int n = (wn * 2 + ni) * 16 + (lane & 15);
      const float bb2 = bias[n];
      #pragma unroll
      for (int i = 0; i < 4; ++i) {
        const int mm = mB * 64 + (wm * 2 + mi) * 16 + 4 * (lane >> 4) + i;
        const int bb = mm >> 6, nr = mm & 63;
        float val = fmaxf(c[mi][ni][i] + bb2, 0.f);
        unsigned short hv = f2h(val);
        if (z == 0)
          vrLin[((size_t)(bb * 8 + r) * 64 + nr) * 64 + n] = hv;
        else if (z == 1)
          qrT2[(size_t)(bb * 8 + r) * 4096 + ((nr >> 4) * 2 + (n >> 5)) * 512 + fragoff(nr, n & 31)] = hv;
        else
          arT2[(size_t)(((bb * 8 + r) * 2 + (n >> 5)) * 4 + (nr >> 4)) * 512 + fragoff(nr, n & 31)] = hv;
      }
    }
}

// ---------------- K3: FUSED Tucker (proven r15 form: CC dbuf, 56 barriers) ----------------
__global__ __launch_bounds__(512) void k_tucker16(
    const unsigned short* __restrict__ vrLin, const unsigned short* __restrict__ qrT2,
    const unsigned short* __restrict__ arT2, const unsigned short* __restrict__ T2,
    float* __restrict__ fout)
{
  const int b = blockIdx.x, vt = blockIdx.y, g = blockIdx.z;
  const int tid = threadIdx.x, lane = tid & 63;
  const int w = __builtin_amdgcn_readfirstlane(tid >> 6);

  __shared__ __align__(16) unsigned short UA[16384];
  __shared__ __align__(16) unsigned short QB[4096];
  __shared__ __align__(16) unsigned short AB[2048];
  __shared__ __align__(16) unsigned short CC[16640];  // [qh][8320]
  __shared__ __align__(16) unsigned short VRL[512];

  f32x4 f[2][2][4];
  #pragma unroll
  for (int qh = 0; qh < 2; ++qh)
    #pragma unroll
    for (int qt = 0; qt < 2; ++qt)
      #pragma unroll
      for (int nt = 0; nt < 4; ++nt)
        f[qh][qt][nt] = (f32x4){0.f, 0.f, 0.f, 0.f};

  for (int r = 0; r < 8; ++r) {
    if (tid < 64)
      *(float4*)&VRL[tid * 8] =
          ((const float4*)(vrLin + (size_t)(b * 8 + r) * 4096 + vt * 512))[tid];
    *(float4*)&QB[tid * 8] = ((const float4*)(qrT2 + (size_t)(b * 8 + r) * 4096))[tid];
    __syncthreads();  // B1

    f16x8 af1[2];
    #pragma unroll
    for (int ks = 0; ks < 2; ++ks)
      #pragma unroll
      for (int j = 0; j < 8; ++j) {
        const int kr = (j & 3) + ((lane >> 4) & 3) * 4 + (j >> 2) * 16;
        af1[ks][j] = __builtin_bit_cast(_Float16, VRL[(lane & 7) * 64 + ks * 32 + kr]);
      }

    for (int lc = 0; lc < 2; ++lc) {
      if (tid < 256)
        ((float4*)AB)[tid] = ((const float4*)(arT2 + ((size_t)((b * 8 + r) * 2 + lc)) * 2048))[tid];

      const unsigned short* tb = T2 + ((size_t)((g * 8 + r) * 256 + lc * 128 + w * 16)) * 1024;
      for (int tg = 0; tg < 4; ++tg) {
        f16x8 bf[4][2];
        f32x4 d[4];
        #pragma unroll
        for (int tt = 0; tt < 4; ++tt) {
          #pragma unroll
          for (int ks = 0; ks < 2; ++ks)
            bf[tt][ks] = *(const f16x8*)&tb[(size_t)(tg * 4 + tt) * 1024 + ks * 512 + lane * 8];
          d[tt] = (f32x4){0.f, 0.f, 0.f, 0.f};
        }
        #pragma unroll
        for (int tt = 0; tt < 4; ++tt)
          #pragma unroll
          for (int ks = 0; ks < 2; ++ks)
            d[tt] = __builtin_amdgcn_mfma_f32_16x16x32_f16(af1[ks], bf[tt][ks], d[tt], 0, 0, 0);
        if (lane < 32) {
          #pragma unroll
          for (int tt = 0; tt < 4; ++tt) {
            const int t = w * 16 + tg * 4 + tt;
            const int lrel = t >> 2;
            const int k0 = (t & 3) * 16 + (lane & 15);
            #pragma unroll
            for (int i = 0; i < 4; ++i) {
              const int v = 4 * (lane >> 4) + i;
              const int row = lrel * 8 + v;
              int off = fragoff(row & 15, k0 & 31);
              int blk = off >> 3;
              blk ^= (blk >> 4) & 3;
              UA[(row >> 4) * 1024 + (k0 >> 5) * 512 + blk * 8 + (off & 7)] = f2h(d[tt][i]);
            }
          }
        }
      }
      __syncthreads();  // B2: UA + AB ready

      f16x8 b3[4], a2[2][2];
      #pragma unroll
      for (int nt = 0; nt < 4; ++nt)
        b3[nt] = *(const f16x8*)&AB[nt * 512 + lane * 8];
      const int lswz = (lane ^ ((lane >> 4) & 3)) * 8;
      #pragma unroll
      for (int mi = 0; mi < 2; ++mi)
        #pragma unroll
        for (int ks = 0; ks < 2; ++ks)
          a2[mi][ks] = *(const f16x8*)&UA[(w * 2 + mi) * 1024 + ks * 512 + lswz];

      // ---- stage2 for BOTH qh (disjoint CC halves) ----
      #pragma unroll
      for (int qh = 0; qh < 2; ++qh) {
        f32x4 c2[2][2];
        #pragma unroll
        for (int mi = 0; mi < 2; ++mi)
          #pragma unroll
          for (int nt = 0; nt < 2; ++nt)
            c2[mi][nt] = (f32x4){0.f, 0.f, 0.f, 0.f};

        f16x8 b2[2][2];
        #pragma unroll
        for (int nt = 0; nt < 2; ++nt)
          #pragma unroll
          for (int ks = 0; ks < 2; ++ks)
            b2[nt][ks] = *(const f16x8*)&QB[(qh * 2 + nt) * 1024 + ks * 512 + lane * 8];

        #pragma unroll
        for (int mi = 0; mi < 2; ++mi)
          #pragma unroll
          for (int nt = 0; nt < 2; ++nt)
            #pragma unroll
            for (int ks = 0; ks < 2; ++ks)
              c2[mi][nt] = __builtin_amdgcn_mfma_f32_16x16x32_f16(a2[mi][ks], b2[nt][ks], c2[mi][nt], 0, 0, 0);

        #pragma unroll
        for (int mi = 0; mi < 2; ++mi)
          #pragma unroll
          for (int nt = 0; nt < 2; ++nt)
            #pragma unroll
            for (int i = 0; i < 4; ++i) {
              const int row = (w * 2 + mi) * 16 + 4 * (lane >> 4) + i;
              const int l = row >> 3, v = row & 7;
              CC[qh * 8320 + (nt * 8 + v) * 520 + fragoff(lane & 15, l)] = f2h(c2[mi][nt][i]);
            }
      }
      __syncthreads();  // B3: both CC halves ready

      // ---- stage3 for BOTH qh ----
      #pragma unroll
      for (int qh = 0; qh < 2; ++qh) {
        f16x8 a3[2];
        #pragma unroll
        for (int qt = 0; qt < 2; ++qt)
          a3[qt] = *(const f16x8*)&CC[qh * 8320 + (qt * 8 + w) * 520 + lane * 8];

        #pragma unroll
        for (int qt = 0; qt < 2; ++qt)
          #pragma unroll
          for (int nt = 0; nt < 4; ++nt)
            f[qh][qt][nt] = __builtin_amdgcn_mfma_f32_16x16x32_f16(a3[qt], b3[nt], f[qh][qt][nt], 0, 0, 0);
      }
      __syncthreads();  // B4
    }
  }

  #pragma unroll
  for (int qh = 0; qh < 2; ++qh)
    #pragma unroll
    for (int qt = 0; qt < 2; ++qt)
      #pragma unroll
      for (int nt = 0; nt < 4; ++nt)
        #pragma unroll
        for (int i = 0; i < 4; ++i) {
          const int q = qh * 32 + qt * 16 + 4 * (lane >> 4) + i;
          const int m = nt * 16 + (lane & 15);
          size_t addr = ((((size_t)b * 64 + vt * 8 + w) * 64 + q) * 64 + m) * 2 + g;
          fout[addr] = f[qh][qt][nt][i];
        }
}

// ---------------- K4: logits via MFMA per (b,v) ----------------
__global__ __launch_bounds__(512) void k_logits2(
    const float* __restrict__ vt, const float* __restrict__ qt,
    const unsigned short* __restrict__ AT16, const float* __restrict__ fout,
    float* __restrict__ Lp)
{
  const int v = blockIdx.x, b = blockIdx.y;
  const int tid = threadIdx.x, lane = tid & 63;
  const int w = __builtin_amdgcn_readfirstlane(tid >> 6);

  __shared__ __align__(16) unsigned int FAu[2048];

  {
    const float4* fo4 = (const float4*)(fout + ((size_t)(b * 64 + v)) * 8192);
    #pragma unroll
    for (int i = 0; i < 4; ++i) {
      int fi = tid + i * 512;
      int q = fi >> 5, mpair = fi & 31;
      float4 x = fo4[fi];
      float s0 = x.x + x.y, s1 = x.z + x.w;
      int m0 = mpair * 2;
      int off = fragoff(q & 15, m0 & 31);
      int idx2 = (((q >> 4) * 2 + (m0 >> 5)) * 512 + off) >> 1;
      unsigned int pk = (unsigned int)f2h(s0) | ((unsigned int)f2h(s1) << 16);
      FAu[idx2] = pk;
    }
  }
  __syncthreads();

  const unsigned short* FAh = (const unsigned short*)FAu;

  f16x8 af[4][2], bf[4][2];
  #pragma unroll
  for (int mt = 0; mt < 4; ++mt)
    #pragma unroll
    for (int ks = 0; ks < 2; ++ks)
      af[mt][ks] = *(const f16x8*)&FAh[(mt * 2 + ks) * 512 + lane * 8];
  #pragma unroll
  for (int nt = 0; nt < 4; ++nt)
    #pragma unroll
    for (int ks = 0; ks < 2; ++ks)
      bf[nt][ks] = *(const f16x8*)&AT16[(size_t)((b * 32 + w * 4 + nt) * 2 + ks) * 512 + lane * 8];

  f32x4 c[4][4];
  #pragma unroll
  for (int mt = 0; mt < 4; ++mt)
    #pragma unroll
    for (int nt = 0; nt < 4; ++nt)
      c[mt][nt] = (f32x4){0.f, 0.f, 0.f, 0.f};

  #pragma unroll
  for (int mt = 0; mt < 4; ++mt)
    #pragma unroll
    for (int nt = 0; nt < 4; ++nt)
      #pragma unroll
      for (int ks = 0; ks < 2; ++ks)
        c[mt][nt] = __builtin_amdgcn_mfma_f32_16x16x32_f16(af[mt][ks], bf[nt][ks], c[mt][nt], 0, 0, 0);

  const int gr = lane >> 4, dl = lane & 15;
  #pragma unroll
  for (int nt = 0; nt < 4; ++nt) {
    const int d = w * 64 + nt * 16 + dl;
    float partial = 0.f;
    #pragma unroll
    for (int mt = 0; mt < 4; ++mt) {
      #pragma unroll
      for (int i = 0; i < 4; ++i) {
        const int q = mt * 16 + gr * 4 + i;
        partial += qt[(b * 64 + q) * 512 + d] * c[mt][nt][i];
      }
    }
    partial += __shfl_xor(partial, 16);
    partial += __shfl_xor(partial, 32);
    const float val = vt[(b * 64 + v) * 512 + d] * partial;
    if (lane < 16) Lp[((size_t)(b * 64 + v)) * 512 + d] = val;
  }
}

// ---------------- K5: reduce logits over v ----------------
__global__ __launch_bounds__(512) void k_lred(const float* __restrict__ Lp, float* __restrict__ Lraw)
{
  const int b = blockIdx.x, d = threadIdx.x;
  float s = 0.f;
  for (int v = 0; v < 64; ++v) s += Lp[(size_t)(b * 64 + v) * 512 + d];
  Lraw[b * 512 + d] = s;
}

// ---------------- K6: batchnorm over batch dim ----------------
__global__ __launch_bounds__(512) void k_bn(
    const float* __restrict__ Lraw, const float* __restrict__ gamma,
    const float* __restrict__ beta, float* __restrict__ lout)
{
  const int d = threadIdx.x;
  float x[16]; float mu = 0.f;
  #pragma unroll
  for (int b = 0; b < 16; ++b) { x[b] = Lraw[b * 512 + d]; mu += x[b]; }
  mu *= (1.f / 16.f);
  float var = 0.f;
  #pragma unroll
  for (int b = 0; b < 16; ++b) { float t = x[b] - mu; var += t * t; }
  var *= (1.f / 16.f);
  const float sc = gamma[d] / sqrtf(var + 1e-5f);
  const float bt = beta[d];
  #pragma unroll
  for (int b = 0; b < 16; ++b) lout[b * 512 + d] = (x[b] - mu) * sc + bt;
}

extern "C" void kernel_launch(void* const* d_in, const int* in_sizes, int n_in,
                              void* d_out, int out_size, void* d_ws, size_t ws_size,
                              hipStream_t stream)
{
  const float* v    = (const float*)d_in[0];
  const float* q    = (const float*)d_in[1];
  const float* a    = (const float*)d_in[2];
  const float* Vv   = (const float*)d_in[3];
  const float* gv   = (const float*)d_in[4];
  const float* bv   = (const float*)d_in[5];
  const float* Vq   = (const float*)d_in[6];
  const float* gq   = (const float*)d_in[7];
  const float* bq   = (const float*)d_in[8];
  const float* Va   = (const float*)d_in[9];
  const float* ga   = (const float*)d_in[10];
  const float* ba   = (const float*)d_in[11];
  const float* Vnv  = (const float*)d_in[12];
  const float* gnv  = (const float*)d_in[13];
  const float* bnv  = (const float*)d_in[14];
  const float* Vnqa = (const float*)d_in[15];
  const float* gnqa = (const float*)d_in[16];
  const float* bnqa = (const float*)d_in[17];
  const float* Tg   = (const float*)d_in[18];
  const float* gamma= (const float*)d_in[19];
  const float* beta = (const float*)d_in[20];

  float* ws   = (float*)d_ws;
  unsigned short* hb = (unsigned short*)(ws + WS_H);
  float* fout = (float*)d_out;
  float* lout = fout + (size_t)16 * 64 * 64 * 64 * 2;

  k_norms_part<<<320, 256, 0, stream>>>(Vv, Vq, Va, Vnv, Vnqa, ws + WS_PRT);
  k_norms_fin<<<19, 64, 0, stream>>>(ws + WS_PRT, ws + WS_NRM);
  k_conv_all<<<352, 256, 0, stream>>>(v, q, a, Vv, Vq, Va, gv, gq, ga,
                                      Vnv, Vnqa, gnv, gnqa, ws + WS_NRM,
                                      hb + H_IN16, hb + H_WB16, hb + H_WN16);
  k_repack2b<<<128, 256, 0, stream>>>(Tg, hb + H_T2);
  k_proj16<<<dim3(8, 16, 3), 256, 0, stream>>>(hb + H_IN16, hb + H_WB16, bv, bq, ba,
                                               ws + WS_VT, ws + WS_QT, ws + WS_AT,
                                               hb + H_RP16, hb + H_AT16);
  k_rproj16<<<dim3(8, 16, 3), 256, 0, stream>>>(hb + H_RP16, hb + H_WN16, bnv, bnqa,
                                                hb + H_VRL, hb + H_QR2, hb + H_AR2);
  k_tucker16<<<dim3(16, 8, 2), 512, 0, stream>>>(hb + H_VRL, hb + H_QR2, hb + H_AR2,
                                                 hb + H_T2, fout);
  k_logits2<<<dim3(64, 16), 512, 0, stream>>>(ws + WS_VT, ws + WS_QT,
                                              hb + H_AT16, fout, ws + WS_LP);
  k_lred<<<16, 512, 0, stream>>>(ws + WS_LP, ws + WS_LR);
  k_bn<<<1, 512, 0, stream>>>(ws + WS_LR, gamma, beta, lout);
}